// Round 19
// baseline (150.641 us; speedup 1.0000x reference)
//
#include <hip/hip_runtime.h>

// Correlation (FlowNet-style), kernel=1, stride=1, md=pad=4.
// B=8, C=128, H=W=192 -> out [8, 81, 192, 192] fp32.
//
// Round-19: R18 (151 us/dispatch) with the accumulator split across two
// blocks to unbind occupancy (41% -> target 60-70%).
//  - tile (b, 8y, 16x) split into g=0 (dy 0..3) and g=1 (dy 4..8) blocks;
//    acc[5][2] = 40 AGPR max (was acc[9][2] = 72). Single pk set (deep
//    prefetch was neutral; -12 VGPR). Est. ~92-104 regs -> 4-5 waves/SIMD.
//  - staged x2 window: 12 rows starting at global rho = 4g; local read row
//    = wy + d for both g. LDS 2 x 4864 uints = 38.9 KB.
//  - total MFMA / LDS-read work unchanged; x2 rows 4..11 staged by both
//    halves (L2-hot); x1 A-frags fetched twice (L3-hot).
//  - grid 4608 = 8 XCDs x 576; g fastest, then xbk (R18's winning order),
//    then yt; XCD k == batch k exactly.
//  - everything else R18-verbatim: f16 MFMA band-GEMM, [row][j24][cp16]
//    staging w/ float4 loads, contiguous-1KB frag reads, stride-132
//    epilogue out-tile, 4-chunk dbuf K-loop.

#define NT 512

typedef __fp16 f16x8 __attribute__((ext_vector_type(8)));
typedef __fp16 p2 __attribute__((ext_vector_type(2)));
typedef float f32x4 __attribute__((ext_vector_type(4)));

union PK { p2 p; unsigned u; };
union FragA { f16x8 v; p2 p[4]; };

static __device__ __forceinline__ unsigned pku(float a, float b) {
  PK z; z.p = __builtin_amdgcn_cvt_pkrtz(a, b); return z.u;
}

__global__ __launch_bounds__(NT, 4)
void corr_kernel(const float* __restrict__ x1g, const float* __restrict__ x2g,
                 float* __restrict__ outg) {
  constexpr int Cc = 128, Hh = 192, Ww = 192;
  constexpr int HW = Hh * Ww;
  constexpr int ROWU = 384;   // uints per staged row (24 j x 16 cp)
  constexpr int NROW = 12;    // staged rows per block
  constexpr int BUFU = 4864;  // 12*384 = 4608 + 256 pad for jt1 overread
  constexpr int PS = 132;     // epilogue plane stride (floats)
  constexpr int NSLOT = NROW * 6 * 16;  // 1152 staging slots

  __shared__ __align__(16) unsigned sm[2 * BUFU];  // 38.9 KB

  // XCD-chunked swizzle: 4608 = 8 XCDs x 576; g fastest, then xbk, then yt.
  const int bid = blockIdx.x;
  const int wid = (bid & 7) * 576 + (bid >> 3);
  const int g   = wid & 1;          // dy-half: 0 -> dy 0..3, 1 -> dy 4..8
  const int t0  = wid >> 1;
  const int xbk = t0 % 12;
  const int t2  = t0 / 12;
  const int yt  = t2 % 24;
  const int b   = t2 / 24;
  const int y0 = yt * 8, x0 = xbk * 16;
  const int dyb = g * 4;            // first dy of this block
  const int ndy = 4 + g;            // 4 or 5

  const int tid = (int)threadIdx.x;
  const int wy = tid >> 6;      // wave = y row
  const int lane = tid & 63;
  const int lr = lane & 15;     // A row p / B col n
  const int lq = lane >> 4;     // k-block

  // ---- A fragments: x1[c][y0+wy][x0+lr], c = kc*32 + lq*8 + e ----
  FragA af[4];
  {
    const float* pA = x1g + (((size_t)b * Cc) * Hh + (y0 + wy)) * Ww + x0 + lr;
#pragma unroll
    for (int kc = 0; kc < 4; ++kc)
#pragma unroll
      for (int r = 0; r < 4; ++r) {
        const int c0 = kc * 32 + lq * 8 + 2 * r;
        af[kc].p[r] = __builtin_amdgcn_cvt_pkrtz(pA[(size_t)c0 * HW],
                                                 pA[(size_t)(c0 + 1) * HW]);
      }
  }

  // ---- staging slots: s -> jf = s%6, cp, row (0..11); 3 per thread ----
  const float* bsrc[3];
  int loff[3];
  bool ok[3], has[3];
#pragma unroll
  for (int k = 0; k < 3; ++k) {
    const int s = tid + k * NT;
    has[k] = (s < NSLOT);
    const int jf = s % 6;
    const int t = s / 6;
    const int cp = t & 15;
    const int row = (t >> 4) & 15;        // 0..11 for valid slots
    const int grow = y0 - 4 + 4 * g + row;  // global x2 row
    const int gcol = x0 - 4 + 4 * jf;
    ok[k] = has[k] && (grow >= 0) && (grow < Hh) && (gcol >= 0) &&
            (gcol <= Ww - 4);
    bsrc[k] = x2g + ((size_t)(b * Cc + 2 * cp) * Hh + (ok[k] ? grow : 0)) * Ww +
              (ok[k] ? gcol : 0);
    loff[k] = row * ROWU + jf * 64 + cp;  // +16*kk per column j = 4jf+kk
  }

  unsigned pk[3][4];
  auto bload = [&](int kc) {
#pragma unroll
    for (int k = 0; k < 3; ++k) {
      float4 v0 = make_float4(0.f, 0.f, 0.f, 0.f), v1 = v0;
      if (ok[k]) {
        const float* p = bsrc[k] + (size_t)(kc * 32) * HW;
        v0 = *(const float4*)p;         // channel 2cp, cols j..j+3
        v1 = *(const float4*)(p + HW);  // channel 2cp+1
      }
      pk[k][0] = pku(v0.x, v1.x);
      pk[k][1] = pku(v0.y, v1.y);
      pk[k][2] = pku(v0.z, v1.z);
      pk[k][3] = pku(v0.w, v1.w);
    }
  };
  auto bwrite = [&](int buf) {
    unsigned* d = sm + buf * BUFU;
#pragma unroll
    for (int k = 0; k < 3; ++k)
      if (has[k]) {
#pragma unroll
        for (int kk = 0; kk < 4; ++kk)
          d[loff[k] + kk * 16] = pk[k][kk];
      }
  };

  f32x4 acc[5][2];
#pragma unroll
  for (int d = 0; d < 5; ++d)
#pragma unroll
    for (int jt = 0; jt < 2; ++jt)
      acc[d][jt] = (f32x4){0.f, 0.f, 0.f, 0.f};

  bload(0);
  bwrite(0);
  bload(1);

  const int rb = lr * 16 + lq * 4;  // uints; wave covers contiguous 1 KB

#pragma unroll
  for (int kc = 0; kc < 4; ++kc) {
    __syncthreads();                       // buf[kc&1] (chunk kc) ready
    if (kc + 1 < 4) bwrite((kc + 1) & 1);  // publish chunk kc+1
    if (kc + 2 < 4) bload(kc + 2);         // issue chunk kc+2 loads
    const unsigned* base = sm + (kc & 1) * BUFU;
#pragma unroll
    for (int d = 0; d < 5; ++d) {
      if (d < 4 || g) {  // wave-uniform: g=0 runs 4 dy, g=1 runs 5
        const unsigned* rp = base + (wy + d) * ROWU + rb;  // local row wy+d
        const f16x8 b0 = *(const f16x8*)(rp);        // j = lr
        const f16x8 b1 = *(const f16x8*)(rp + 256);  // j = 16+lr
        acc[d][0] = __builtin_amdgcn_mfma_f32_16x16x32_f16(af[kc].v, b0,
                                                           acc[d][0], 0, 0, 0);
        acc[d][1] = __builtin_amdgcn_mfma_f32_16x16x32_f16(af[kc].v, b1,
                                                           acc[d][1], 0, 0, 0);
      }
    }
  }

  // ---- epilogue: band extract -> LDS out-tile [ndy*9][PS] -> coalesced ----
  __syncthreads();
  float* ot = (float*)sm;  // up to 45*132*4 = 23.8 KB
  const float invc = 1.0f / 128.0f;
#pragma unroll
  for (int d = 0; d < 5; ++d) {
    if (d < 4 || g) {
#pragma unroll
      for (int jt = 0; jt < 2; ++jt)
#pragma unroll
        for (int r = 0; r < 4; ++r) {
          const int p = 4 * lq + r;         // x pixel (C row)
          const int dx = jt * 16 + lr - p;  // C col - row
          if (dx >= 0 && dx < 9)
            ot[(d * 9 + dx) * PS + wy * 16 + p] = acc[d][jt][r] * invc;
        }
    }
  }
  __syncthreads();

  const int nf4 = ndy * 288;               // planes * 8y * 4 float4
  for (int s = tid; s < nf4; s += NT) {
    const int d = s >> 5;                   // plane within block (0..ndy*9-1)
    const int yy = (s >> 2) & 7;
    const int xf = s & 3;
    const float4 v = *(const float4*)&ot[d * PS + yy * 16 + xf * 4];
    *(float4*)&outg[(((size_t)b * 81 + dyb * 9 + d) * Hh + (y0 + yy)) * Ww +
                    x0 + 4 * xf] = v;
  }
}

extern "C" void kernel_launch(void* const* d_in, const int* in_sizes, int n_in,
                              void* d_out, int out_size, void* d_ws, size_t ws_size,
                              hipStream_t stream) {
  const float* x1 = (const float*)d_in[0];
  const float* x2 = (const float*)d_in[1];
  float* out = (float*)d_out;
  // grid: 8 b x 24 yt x 12 xbk x 2 dy-halves = 4608 blocks (8 XCDs x 576)
  corr_kernel<<<dim3(4608), dim3(NT), 0, stream>>>(x1, x2, out);
}